// Round 3
// baseline (2974.896 us; speedup 1.0000x reference)
//
#include <hip/hip_runtime.h>

#define NN 100000
#define NF 128
#define NE 1600000
#define NBK 782   // ceil(NN/128) buckets of 128 dst nodes
#define CH 8192   // edges per binning chunk

// --------------------------------------------------------------- hist + deg
// One pass over edge_index: deg[src]++ (global), bucket counts via LDS hist.
__global__ __launch_bounds__(256) void k_hist2(const int* __restrict__ src,
                                               const int* __restrict__ dst,
                                               int* __restrict__ deg,
                                               int* __restrict__ bcnt) {
  __shared__ int h[1024];
  for (int i = threadIdx.x; i < 1024; i += 256) h[i] = 0;
  __syncthreads();
  const int gid = blockIdx.x * 256 + threadIdx.x;
  const int stride = gridDim.x * 256;
  for (int e = gid; e < NE; e += stride) {
    atomicAdd(&deg[src[e]], 1);
    atomicAdd(&h[dst[e] >> 7], 1);
  }
  __syncthreads();
  for (int i = threadIdx.x; i < NBK; i += 256)
    if (h[i]) atomicAdd(&bcnt[i], h[i]);
}

// ---------------------------------------------- block-wide exclusive scan
// 256 threads, 1024 padded elements, 4 contiguous per thread.
__device__ inline void block_scan(const int* hist, int* lofs, int* wsum) {
  const int t = threadIdx.x;
  const int b4 = t * 4;
  const int h0 = hist[b4], h1 = hist[b4 + 1], h2 = hist[b4 + 2], h3 = hist[b4 + 3];
  const int tsum = h0 + h1 + h2 + h3;
  const int lane = t & 63, w = t >> 6;
  int s = tsum;
#pragma unroll
  for (int o = 1; o < 64; o <<= 1) {
    const int u = __shfl_up(s, o);
    if (lane >= o) s += u;
  }
  if (lane == 63) wsum[w] = s;
  __syncthreads();
  int add = 0;
  for (int i = 0; i < w; ++i) add += wsum[i];
  const int ex = add + s - tsum;
  lofs[b4] = ex;
  lofs[b4 + 1] = ex + h0;
  lofs[b4 + 2] = ex + h0 + h1;
  lofs[b4 + 3] = ex + h0 + h1 + h2;
}

// scan bucket counts -> boffs (exclusive, +sentinel) and cursor copy
__global__ __launch_bounds__(256) void k_bscan(const int* __restrict__ bcnt,
                                               int* __restrict__ boffs,
                                               int* __restrict__ bcursor) {
  __shared__ int hist[1024];
  __shared__ int lofs[1024];
  __shared__ int wsum[4];
  const int t = threadIdx.x;
  for (int i = t; i < 1024; i += 256) hist[i] = (i < NBK) ? bcnt[i] : 0;
  __syncthreads();
  block_scan(hist, lofs, wsum);
  __syncthreads();
  for (int i = t; i < 1024; i += 256) {
    if (i <= NBK) boffs[i] = lofs[i];  // lofs[NBK] == NE (padded zeros)
    if (i < NBK) bcursor[i] = lofs[i];
  }
}

// ------------------------------------------------ LDS-staged bucket binning
// Per chunk: LDS hist -> scan -> global range reservation -> local scatter ->
// coalesced flush of packed ((dst&127)<<17 | src) words.
__global__ __launch_bounds__(256) void k_bin(const int* __restrict__ src,
                                             const int* __restrict__ dst,
                                             int* __restrict__ bcursor,
                                             int* __restrict__ packed) {
  __shared__ int hist[1024];
  __shared__ int lofs[1024];
  __shared__ int wsum[4];
  __shared__ int gofs[NBK];
  __shared__ int list[CH];
  __shared__ unsigned short blist[CH];
  const int t = threadIdx.x;
  const int e0 = blockIdx.x * CH;
  const int n = min(CH, NE - e0);

  for (int i = t; i < 1024; i += 256) hist[i] = 0;
  __syncthreads();
  for (int i = t; i < n; i += 256) atomicAdd(&hist[dst[e0 + i] >> 7], 1);
  __syncthreads();
  block_scan(hist, lofs, wsum);
  __syncthreads();
  // reserve global ranges; re-zero hist for the ranking pass
  for (int b = t; b < NBK; b += 256) {
    const int cnt = hist[b];
    gofs[b] = cnt ? atomicAdd(&bcursor[b], cnt) : 0;
    hist[b] = 0;
  }
  __syncthreads();
  // rank within bucket + local scatter into LDS
  for (int i = t; i < n; i += 256) {
    const int d = dst[e0 + i];
    const int s = src[e0 + i];
    const int b = d >> 7;
    const int r = atomicAdd(&hist[b], 1);
    const int q = lofs[b] + r;
    list[q] = ((d & 127) << 17) | s;
    blist[q] = (unsigned short)b;
  }
  __syncthreads();
  // coalesced flush: consecutive q -> consecutive global within each segment
  for (int q = t; q < n; q += 256) {
    const int b = blist[q];
    packed[gofs[b] + (q - lofs[b])] = list[q];
  }
}

// ------------------------------------------- LDS-accumulator aggregation
// One block per 128-dst bucket; wave per edge (float2/lane row gather),
// accumulate via LDS float atomics; single coalesced row write-out.
__global__ __launch_bounds__(512) void k_agg2(const float* __restrict__ feat,
                                              const int* __restrict__ boffs,
                                              const int* __restrict__ packed,
                                              float* __restrict__ out) {
  __shared__ float acc[128 * 128];  // 64 KB
  const int t = threadIdx.x;
  const float4 z4 = make_float4(0.f, 0.f, 0.f, 0.f);
  for (int i = t; i < 4096; i += 512) ((float4*)acc)[i] = z4;
  __syncthreads();

  const int b = blockIdx.x;
  const int beg = boffs[b], end = boffs[b + 1];
  const int w = t >> 6;
  const int c = (t & 63) * 2;

  int e = beg + w;
  for (; e + 24 < end; e += 32) {  // 8 waves x unroll 4
    const int p0 = packed[e];
    const int p1 = packed[e + 8];
    const int p2 = packed[e + 16];
    const int p3 = packed[e + 24];
    const float2 v0 = *(const float2*)(feat + (size_t)(p0 & 0x1FFFF) * NF + c);
    const float2 v1 = *(const float2*)(feat + (size_t)(p1 & 0x1FFFF) * NF + c);
    const float2 v2 = *(const float2*)(feat + (size_t)(p2 & 0x1FFFF) * NF + c);
    const float2 v3 = *(const float2*)(feat + (size_t)(p3 & 0x1FFFF) * NF + c);
    float* a0 = acc + (p0 >> 17) * NF + c;
    float* a1 = acc + (p1 >> 17) * NF + c;
    float* a2 = acc + (p2 >> 17) * NF + c;
    float* a3 = acc + (p3 >> 17) * NF + c;
    atomicAdd(a0, v0.x); atomicAdd(a0 + 1, v0.y);
    atomicAdd(a1, v1.x); atomicAdd(a1 + 1, v1.y);
    atomicAdd(a2, v2.x); atomicAdd(a2 + 1, v2.y);
    atomicAdd(a3, v3.x); atomicAdd(a3 + 1, v3.y);
  }
  for (; e < end; e += 8) {
    const int p = packed[e];
    const float2 v = *(const float2*)(feat + (size_t)(p & 0x1FFFF) * NF + c);
    float* a = acc + (p >> 17) * NF + c;
    atomicAdd(a, v.x); atomicAdd(a + 1, v.y);
  }
  __syncthreads();

  const int node0 = b << 7;
  const int nrows = min(128, NN - node0);
  float4* op = (float4*)(out + (size_t)node0 * NF);
  for (int i = t; i < nrows * 32; i += 512) op[i] = ((const float4*)acc)[i];
}

// ---------------------------------------------------------------- fused GEMM
// (unchanged from round 2 — exact)
template <int RELU>
__global__ __launch_bounds__(256) void k_gemm(const float* __restrict__ A1,
                                              const float* __restrict__ A2,
                                              const float* __restrict__ B1,
                                              const float* __restrict__ B2,
                                              const float* __restrict__ bias,
                                              float* __restrict__ out) {
  __shared__ __align__(16) float At[32][72];
  __shared__ __align__(16) float Bt[32][136];

  const int tid = threadIdx.x;
  const int n0 = blockIdx.x * 64;
  const int tx = tid & 15;
  const int ty = tid >> 4;

  float acc[4][8];
#pragma unroll
  for (int r = 0; r < 4; ++r)
#pragma unroll
    for (int c = 0; c < 8; ++c) acc[r][c] = 0.f;

  const int li = tid >> 2;
  const int lq = tid & 3;
  const int bj = tid >> 1;
  const int bh = tid & 1;

  for (int k0 = 0; k0 < 256; k0 += 32) {
    const float* __restrict__ A = (k0 < 128) ? A1 : A2;
    const float* __restrict__ B = (k0 < 128) ? B1 : B2;
    const int kb = k0 & 127;

    {
      float4 v0 = make_float4(0.f, 0.f, 0.f, 0.f), v1 = v0;
      const int node = n0 + li;
      if (node < NN) {
        const float* p = A + (size_t)node * NF + kb + lq * 8;
        v0 = *reinterpret_cast<const float4*>(p);
        v1 = *reinterpret_cast<const float4*>(p + 4);
      }
      const int kk = lq * 8;
      At[kk + 0][li] = v0.x; At[kk + 1][li] = v0.y;
      At[kk + 2][li] = v0.z; At[kk + 3][li] = v0.w;
      At[kk + 4][li] = v1.x; At[kk + 5][li] = v1.y;
      At[kk + 6][li] = v1.z; At[kk + 7][li] = v1.w;
    }
    {
      const float* p = B + (size_t)bj * NF + kb + bh * 16;
      const float4 w0 = *reinterpret_cast<const float4*>(p);
      const float4 w1 = *reinterpret_cast<const float4*>(p + 4);
      const float4 w2 = *reinterpret_cast<const float4*>(p + 8);
      const float4 w3 = *reinterpret_cast<const float4*>(p + 12);
      const int kk = bh * 16;
      Bt[kk + 0][bj] = w0.x;  Bt[kk + 1][bj] = w0.y;
      Bt[kk + 2][bj] = w0.z;  Bt[kk + 3][bj] = w0.w;
      Bt[kk + 4][bj] = w1.x;  Bt[kk + 5][bj] = w1.y;
      Bt[kk + 6][bj] = w1.z;  Bt[kk + 7][bj] = w1.w;
      Bt[kk + 8][bj] = w2.x;  Bt[kk + 9][bj] = w2.y;
      Bt[kk + 10][bj] = w2.z; Bt[kk + 11][bj] = w2.w;
      Bt[kk + 12][bj] = w3.x; Bt[kk + 13][bj] = w3.y;
      Bt[kk + 14][bj] = w3.z; Bt[kk + 15][bj] = w3.w;
    }
    __syncthreads();

#pragma unroll
    for (int kk = 0; kk < 32; ++kk) {
      const float4 a = *reinterpret_cast<const float4*>(&At[kk][ty * 4]);
      const float4 b0 = *reinterpret_cast<const float4*>(&Bt[kk][tx * 4]);
      const float4 b1 = *reinterpret_cast<const float4*>(&Bt[kk][64 + tx * 4]);
      const float av[4] = {a.x, a.y, a.z, a.w};
      const float bv[8] = {b0.x, b0.y, b0.z, b0.w, b1.x, b1.y, b1.z, b1.w};
#pragma unroll
      for (int r = 0; r < 4; ++r)
#pragma unroll
        for (int c = 0; c < 8; ++c) acc[r][c] += av[r] * bv[c];
    }
    __syncthreads();
  }

  float bv[8];
#pragma unroll
  for (int c = 0; c < 4; ++c) {
    bv[c] = bias[tx * 4 + c];
    bv[4 + c] = bias[64 + tx * 4 + c];
  }
#pragma unroll
  for (int r = 0; r < 4; ++r) {
    const int node = n0 + ty * 4 + r;
    if (node < NN) {
      float4 o0, o1;
      o0.x = acc[r][0] + bv[0]; o0.y = acc[r][1] + bv[1];
      o0.z = acc[r][2] + bv[2]; o0.w = acc[r][3] + bv[3];
      o1.x = acc[r][4] + bv[4]; o1.y = acc[r][5] + bv[5];
      o1.z = acc[r][6] + bv[6]; o1.w = acc[r][7] + bv[7];
      if (RELU) {
        o0.x = fmaxf(o0.x, 0.f); o0.y = fmaxf(o0.y, 0.f);
        o0.z = fmaxf(o0.z, 0.f); o0.w = fmaxf(o0.w, 0.f);
        o1.x = fmaxf(o1.x, 0.f); o1.y = fmaxf(o1.y, 0.f);
        o1.z = fmaxf(o1.z, 0.f); o1.w = fmaxf(o1.w, 0.f);
      }
      float* po = out + (size_t)node * NF;
      *reinterpret_cast<float4*>(po + tx * 4) = o0;
      *reinterpret_cast<float4*>(po + 64 + tx * 4) = o1;
    }
  }
}

// ------------------------------------- layer-3 collapsed weighted reductions
__global__ __launch_bounds__(256) void k_reduce3(const float* __restrict__ h,
                                                 const int* __restrict__ deg,
                                                 float* __restrict__ S) {
  const int t = blockIdx.x * 256 + threadIdx.x;
  const int f = t & 127;
  const int i0 = t >> 7;
  float a1 = 0.f, a2 = 0.f;
  for (int i = i0; i < NN; i += 512) {
    const float v = h[(size_t)i * NF + f];
    a1 += v;
    a2 += (float)deg[i] * v;
  }
  atomicAdd(&S[f], a1);
  atomicAdd(&S[128 + f], a2);
}

__global__ __launch_bounds__(128) void k_final(const float* __restrict__ S,
                                               const float* __restrict__ W3rel,
                                               const float* __restrict__ W3root,
                                               const float* __restrict__ b3,
                                               float* __restrict__ out) {
  const int f = threadIdx.x;
  float v = W3rel[f] * S[128 + f] + W3root[f] * S[f];
#pragma unroll
  for (int o = 32; o > 0; o >>= 1) v += __shfl_down(v, o);
  __shared__ float tmp[2];
  if ((f & 63) == 0) tmp[f >> 6] = v;
  __syncthreads();
  if (f == 0) out[0] = (tmp[0] + tmp[1]) * (1.0f / NN) + b3[0];
}

// ---------------------------------------------------------------------------
extern "C" void kernel_launch(void* const* d_in, const int* in_sizes, int n_in,
                              void* d_out, int out_size, void* d_ws, size_t ws_size,
                              hipStream_t stream) {
  const float* x = (const float*)d_in[0];
  const int* ei = (const int*)d_in[1];
  const float* W1rel = (const float*)d_in[2];
  const float* b1 = (const float*)d_in[3];
  const float* W1root = (const float*)d_in[4];
  const float* W2rel = (const float*)d_in[5];
  const float* b2 = (const float*)d_in[6];
  const float* W2root = (const float*)d_in[7];
  const float* W3rel = (const float*)d_in[8];
  const float* b3 = (const float*)d_in[9];
  const float* W3root = (const float*)d_in[10];

  const int* src = ei;       // edge_index[0]
  const int* dst = ei + NE;  // edge_index[1]

  char* ws = (char*)d_ws;
  size_t off = 0;
  float* bufA = (float*)(ws + off); off += (size_t)NN * NF * 4;   // 51.2 MB
  float* bufB = (float*)(ws + off); off += (size_t)NN * NF * 4;   // 51.2 MB
  int* deg     = (int*)(ws + off);  off += (size_t)NN * 4;        // 400 KB
  int* bcnt    = (int*)(ws + off);  off += 1024 * 4;
  int* boffs   = (int*)(ws + off);  off += 1024 * 4;
  int* bcursor = (int*)(ws + off);  off += 1024 * 4;
  float* S     = (float*)(ws + off); off += 256 * 4;
  int* packed  = (int*)(ws + off);  off += (size_t)NE * 4;        // 6.4 MB
  float* outp = (float*)d_out;

  hipMemsetAsync(deg, 0, (size_t)NN * sizeof(int), stream);
  hipMemsetAsync(bcnt, 0, 1024 * sizeof(int), stream);
  hipMemsetAsync(S, 0, 256 * sizeof(float), stream);

  // build coarse-bucketed edge list
  k_hist2<<<391, 256, 0, stream>>>(src, dst, deg, bcnt);
  k_bscan<<<1, 256, 0, stream>>>(bcnt, boffs, bcursor);
  k_bin<<<(NE + CH - 1) / CH, 256, 0, stream>>>(src, dst, bcursor, packed);

  // layer 1: agg(x) -> bufA; h1 = relu(gemm) in-place into bufA
  k_agg2<<<NBK, 512, 0, stream>>>(x, boffs, packed, bufA);
  k_gemm<1><<<(NN + 63) / 64, 256, 0, stream>>>(bufA, x, W1rel, W1root, b1, bufA);

  // layer 2: agg(h1) -> bufB; h2 = relu(gemm) in-place into bufB
  k_agg2<<<NBK, 512, 0, stream>>>(bufA, boffs, packed, bufB);
  k_gemm<1><<<(NN + 63) / 64, 256, 0, stream>>>(bufB, bufA, W2rel, W2root, b2, bufB);

  // layer 3 collapsed
  k_reduce3<<<256, 256, 0, stream>>>(bufB, deg, S);
  k_final<<<1, 128, 0, stream>>>(S, W3rel, W3root, b3, outp);
}

// Round 4
// 595.659 us; speedup vs baseline: 4.9943x; 4.9943x over previous
//
#include <hip/hip_runtime.h>

#define NN 100000
#define NF 128
#define NE 1600000
#define NBK 782   // ceil(NN/128) buckets of 128 dst nodes
#define CH 8192   // edges per binning chunk
#define MAXB 2816 // max edges per bucket (mean 2046, sigma~45; +17 sigma headroom)

// --------------------------------------------------------------- hist + deg
// One pass over edge_index: deg[src]++ (global), bucket counts via LDS hist.
__global__ __launch_bounds__(256) void k_hist2(const int* __restrict__ src,
                                               const int* __restrict__ dst,
                                               int* __restrict__ deg,
                                               int* __restrict__ bcnt) {
  __shared__ int h[1024];
  for (int i = threadIdx.x; i < 1024; i += 256) h[i] = 0;
  __syncthreads();
  const int gid = blockIdx.x * 256 + threadIdx.x;
  const int stride = gridDim.x * 256;
  for (int e = gid; e < NE; e += stride) {
    atomicAdd(&deg[src[e]], 1);
    atomicAdd(&h[dst[e] >> 7], 1);
  }
  __syncthreads();
  for (int i = threadIdx.x; i < NBK; i += 256)
    if (h[i]) atomicAdd(&bcnt[i], h[i]);
}

// ---------------------------------------------- block-wide exclusive scan
// 256 threads, 1024 padded elements, 4 contiguous per thread.
__device__ inline void block_scan(const int* hist, int* lofs, int* wsum) {
  const int t = threadIdx.x;
  const int b4 = t * 4;
  const int h0 = hist[b4], h1 = hist[b4 + 1], h2 = hist[b4 + 2], h3 = hist[b4 + 3];
  const int tsum = h0 + h1 + h2 + h3;
  const int lane = t & 63, w = t >> 6;
  int s = tsum;
#pragma unroll
  for (int o = 1; o < 64; o <<= 1) {
    const int u = __shfl_up(s, o);
    if (lane >= o) s += u;
  }
  if (lane == 63) wsum[w] = s;
  __syncthreads();
  int add = 0;
  for (int i = 0; i < w; ++i) add += wsum[i];
  const int ex = add + s - tsum;
  lofs[b4] = ex;
  lofs[b4 + 1] = ex + h0;
  lofs[b4 + 2] = ex + h0 + h1;
  lofs[b4 + 3] = ex + h0 + h1 + h2;
}

// scan bucket counts -> boffs (exclusive, +sentinel) and cursor copy
__global__ __launch_bounds__(256) void k_bscan(const int* __restrict__ bcnt,
                                               int* __restrict__ boffs,
                                               int* __restrict__ bcursor) {
  __shared__ int hist[1024];
  __shared__ int lofs[1024];
  __shared__ int wsum[4];
  const int t = threadIdx.x;
  for (int i = t; i < 1024; i += 256) hist[i] = (i < NBK) ? bcnt[i] : 0;
  __syncthreads();
  block_scan(hist, lofs, wsum);
  __syncthreads();
  for (int i = t; i < 1024; i += 256) {
    if (i <= NBK) boffs[i] = lofs[i];  // lofs[NBK] == NE (padded zeros)
    if (i < NBK) bcursor[i] = lofs[i];
  }
}

// ------------------------------------------------ LDS-staged bucket binning
// Per chunk: LDS hist -> scan -> global range reservation -> local scatter ->
// coalesced flush of packed ((dst&127)<<17 | src) words, grouped by bucket.
__global__ __launch_bounds__(256) void k_bin(const int* __restrict__ src,
                                             const int* __restrict__ dst,
                                             int* __restrict__ bcursor,
                                             int* __restrict__ packed) {
  __shared__ int hist[1024];
  __shared__ int lofs[1024];
  __shared__ int wsum[4];
  __shared__ int gofs[NBK];
  __shared__ int list[CH];
  __shared__ unsigned short blist[CH];
  const int t = threadIdx.x;
  const int e0 = blockIdx.x * CH;
  const int n = min(CH, NE - e0);

  for (int i = t; i < 1024; i += 256) hist[i] = 0;
  __syncthreads();
  for (int i = t; i < n; i += 256) atomicAdd(&hist[dst[e0 + i] >> 7], 1);
  __syncthreads();
  block_scan(hist, lofs, wsum);
  __syncthreads();
  for (int b = t; b < NBK; b += 256) {
    const int cnt = hist[b];
    gofs[b] = cnt ? atomicAdd(&bcursor[b], cnt) : 0;
    hist[b] = 0;
  }
  __syncthreads();
  for (int i = t; i < n; i += 256) {
    const int d = dst[e0 + i];
    const int s = src[e0 + i];
    const int b = d >> 7;
    const int r = atomicAdd(&hist[b], 1);
    const int q = lofs[b] + r;
    list[q] = ((d & 127) << 17) | s;
    blist[q] = (unsigned short)b;
  }
  __syncthreads();
  for (int q = t; q < n; q += 256) {
    const int b = blist[q];
    packed[gofs[b] + (q - lofs[b])] = list[q];
  }
}

// --------------------------------- second-level sort: exact CSR per bucket
// One block per bucket. Loads its packed segment to LDS, exact-sorts by the
// 7-bit local dst, writes per-node offsets + coalesced srcs IN PLACE over
// packed (safe: full segment is in LDS before the overwrite).
__global__ __launch_bounds__(256) void k_sort2(int* __restrict__ packed,
                                               const int* __restrict__ boffs,
                                               int* __restrict__ offs) {
  __shared__ int plist[MAXB];
  __shared__ int slist[MAXB];
  __shared__ int hist[128];
  __shared__ int lofs[128];
  __shared__ int wsum2[2];
  const int b = blockIdx.x, t = threadIdx.x;
  const int beg = boffs[b], end = boffs[b + 1];
  const int n = min(end - beg, MAXB);

  for (int i = t; i < n; i += 256) plist[i] = packed[beg + i];
  if (t < 128) hist[t] = 0;
  __syncthreads();
  for (int i = t; i < n; i += 256) atomicAdd(&hist[plist[i] >> 17], 1);
  __syncthreads();
  // exclusive scan of hist[0..127] (waves 0-1 carry real values)
  int s = (t < 128) ? hist[t] : 0;
  {
    const int lane = t & 63;
#pragma unroll
    for (int o = 1; o < 64; o <<= 1) {
      const int u = __shfl_up(s, o);
      if (lane >= o) s += u;
    }
    if (t < 128 && lane == 63) wsum2[t >> 6] = s;
  }
  __syncthreads();
  if (t < 128) {
    const int ex = s - hist[t] + ((t >= 64) ? wsum2[0] : 0);
    lofs[t] = ex;
    const int node = (b << 7) + t;
    if (node < NN) offs[node] = beg + ex;
    hist[t] = 0;
  }
  __syncthreads();
  for (int i = t; i < n; i += 256) {
    const int p = plist[i];
    const int ld = p >> 17;
    const int r = atomicAdd(&hist[ld], 1);
    slist[lofs[ld] + r] = p & 0x1FFFF;
  }
  __syncthreads();
  for (int i = t; i < n; i += 256) packed[beg + i] = slist[i];
}

// --------------------------------------------- gather-based aggregation
// one wave per dst node; lane handles 2 consecutive feats (512B/row coalesced)
__global__ __launch_bounds__(256) void k_agg(const float* __restrict__ feat,
                                             const int* __restrict__ offs,
                                             const int* __restrict__ srcs,
                                             float* __restrict__ out) {
  const int node = blockIdx.x * 4 + (threadIdx.x >> 6);
  if (node >= NN) return;
  const int lane = threadIdx.x & 63;
  const int c = lane * 2;
  const int beg = offs[node];
  const int end = (node == NN - 1) ? NE : offs[node + 1];

  float a0x = 0.f, a0y = 0.f, a1x = 0.f, a1y = 0.f;
  float a2x = 0.f, a2y = 0.f, a3x = 0.f, a3y = 0.f;
  int e = beg;
  for (; e + 4 <= end; e += 4) {
    const int s0 = srcs[e], s1 = srcs[e + 1], s2 = srcs[e + 2], s3 = srcs[e + 3];
    const float2 v0 = *reinterpret_cast<const float2*>(feat + (size_t)s0 * NF + c);
    const float2 v1 = *reinterpret_cast<const float2*>(feat + (size_t)s1 * NF + c);
    const float2 v2 = *reinterpret_cast<const float2*>(feat + (size_t)s2 * NF + c);
    const float2 v3 = *reinterpret_cast<const float2*>(feat + (size_t)s3 * NF + c);
    a0x += v0.x; a0y += v0.y;
    a1x += v1.x; a1y += v1.y;
    a2x += v2.x; a2y += v2.y;
    a3x += v3.x; a3y += v3.y;
  }
  for (; e < end; ++e) {
    const int s = srcs[e];
    const float2 v = *reinterpret_cast<const float2*>(feat + (size_t)s * NF + c);
    a0x += v.x; a0y += v.y;
  }
  float2 r;
  r.x = (a0x + a1x) + (a2x + a3x);
  r.y = (a0y + a1y) + (a2y + a3y);
  *reinterpret_cast<float2*>(out + (size_t)node * NF + c) = r;
}

// ---------------------------------------------------------------- fused GEMM
template <int RELU>
__global__ __launch_bounds__(256) void k_gemm(const float* __restrict__ A1,
                                              const float* __restrict__ A2,
                                              const float* __restrict__ B1,
                                              const float* __restrict__ B2,
                                              const float* __restrict__ bias,
                                              float* __restrict__ out) {
  __shared__ __align__(16) float At[32][72];
  __shared__ __align__(16) float Bt[32][136];

  const int tid = threadIdx.x;
  const int n0 = blockIdx.x * 64;
  const int tx = tid & 15;
  const int ty = tid >> 4;

  float acc[4][8];
#pragma unroll
  for (int r = 0; r < 4; ++r)
#pragma unroll
    for (int c = 0; c < 8; ++c) acc[r][c] = 0.f;

  const int li = tid >> 2;
  const int lq = tid & 3;
  const int bj = tid >> 1;
  const int bh = tid & 1;

  for (int k0 = 0; k0 < 256; k0 += 32) {
    const float* __restrict__ A = (k0 < 128) ? A1 : A2;
    const float* __restrict__ B = (k0 < 128) ? B1 : B2;
    const int kb = k0 & 127;

    {
      float4 v0 = make_float4(0.f, 0.f, 0.f, 0.f), v1 = v0;
      const int node = n0 + li;
      if (node < NN) {
        const float* p = A + (size_t)node * NF + kb + lq * 8;
        v0 = *reinterpret_cast<const float4*>(p);
        v1 = *reinterpret_cast<const float4*>(p + 4);
      }
      const int kk = lq * 8;
      At[kk + 0][li] = v0.x; At[kk + 1][li] = v0.y;
      At[kk + 2][li] = v0.z; At[kk + 3][li] = v0.w;
      At[kk + 4][li] = v1.x; At[kk + 5][li] = v1.y;
      At[kk + 6][li] = v1.z; At[kk + 7][li] = v1.w;
    }
    {
      const float* p = B + (size_t)bj * NF + kb + bh * 16;
      const float4 w0 = *reinterpret_cast<const float4*>(p);
      const float4 w1 = *reinterpret_cast<const float4*>(p + 4);
      const float4 w2 = *reinterpret_cast<const float4*>(p + 8);
      const float4 w3 = *reinterpret_cast<const float4*>(p + 12);
      const int kk = bh * 16;
      Bt[kk + 0][bj] = w0.x;  Bt[kk + 1][bj] = w0.y;
      Bt[kk + 2][bj] = w0.z;  Bt[kk + 3][bj] = w0.w;
      Bt[kk + 4][bj] = w1.x;  Bt[kk + 5][bj] = w1.y;
      Bt[kk + 6][bj] = w1.z;  Bt[kk + 7][bj] = w1.w;
      Bt[kk + 8][bj] = w2.x;  Bt[kk + 9][bj] = w2.y;
      Bt[kk + 10][bj] = w2.z; Bt[kk + 11][bj] = w2.w;
      Bt[kk + 12][bj] = w3.x; Bt[kk + 13][bj] = w3.y;
      Bt[kk + 14][bj] = w3.z; Bt[kk + 15][bj] = w3.w;
    }
    __syncthreads();

#pragma unroll
    for (int kk = 0; kk < 32; ++kk) {
      const float4 a = *reinterpret_cast<const float4*>(&At[kk][ty * 4]);
      const float4 b0 = *reinterpret_cast<const float4*>(&Bt[kk][tx * 4]);
      const float4 b1 = *reinterpret_cast<const float4*>(&Bt[kk][64 + tx * 4]);
      const float av[4] = {a.x, a.y, a.z, a.w};
      const float bv[8] = {b0.x, b0.y, b0.z, b0.w, b1.x, b1.y, b1.z, b1.w};
#pragma unroll
      for (int r = 0; r < 4; ++r)
#pragma unroll
        for (int c = 0; c < 8; ++c) acc[r][c] += av[r] * bv[c];
    }
    __syncthreads();
  }

  float bv[8];
#pragma unroll
  for (int c = 0; c < 4; ++c) {
    bv[c] = bias[tx * 4 + c];
    bv[4 + c] = bias[64 + tx * 4 + c];
  }
#pragma unroll
  for (int r = 0; r < 4; ++r) {
    const int node = n0 + ty * 4 + r;
    if (node < NN) {
      float4 o0, o1;
      o0.x = acc[r][0] + bv[0]; o0.y = acc[r][1] + bv[1];
      o0.z = acc[r][2] + bv[2]; o0.w = acc[r][3] + bv[3];
      o1.x = acc[r][4] + bv[4]; o1.y = acc[r][5] + bv[5];
      o1.z = acc[r][6] + bv[6]; o1.w = acc[r][7] + bv[7];
      if (RELU) {
        o0.x = fmaxf(o0.x, 0.f); o0.y = fmaxf(o0.y, 0.f);
        o0.z = fmaxf(o0.z, 0.f); o0.w = fmaxf(o0.w, 0.f);
        o1.x = fmaxf(o1.x, 0.f); o1.y = fmaxf(o1.y, 0.f);
        o1.z = fmaxf(o1.z, 0.f); o1.w = fmaxf(o1.w, 0.f);
      }
      float* po = out + (size_t)node * NF;
      *reinterpret_cast<float4*>(po + tx * 4) = o0;
      *reinterpret_cast<float4*>(po + 64 + tx * 4) = o1;
    }
  }
}

// ------------------------------------- layer-3 collapsed weighted reductions
__global__ __launch_bounds__(256) void k_reduce3(const float* __restrict__ h,
                                                 const int* __restrict__ deg,
                                                 float* __restrict__ S) {
  const int t = blockIdx.x * 256 + threadIdx.x;
  const int f = t & 127;
  const int i0 = t >> 7;
  float a1 = 0.f, a2 = 0.f;
  for (int i = i0; i < NN; i += 512) {
    const float v = h[(size_t)i * NF + f];
    a1 += v;
    a2 += (float)deg[i] * v;
  }
  atomicAdd(&S[f], a1);
  atomicAdd(&S[128 + f], a2);
}

__global__ __launch_bounds__(128) void k_final(const float* __restrict__ S,
                                               const float* __restrict__ W3rel,
                                               const float* __restrict__ W3root,
                                               const float* __restrict__ b3,
                                               float* __restrict__ out) {
  const int f = threadIdx.x;
  float v = W3rel[f] * S[128 + f] + W3root[f] * S[f];
#pragma unroll
  for (int o = 32; o > 0; o >>= 1) v += __shfl_down(v, o);
  __shared__ float tmp[2];
  if ((f & 63) == 0) tmp[f >> 6] = v;
  __syncthreads();
  if (f == 0) out[0] = (tmp[0] + tmp[1]) * (1.0f / NN) + b3[0];
}

// ---------------------------------------------------------------------------
extern "C" void kernel_launch(void* const* d_in, const int* in_sizes, int n_in,
                              void* d_out, int out_size, void* d_ws, size_t ws_size,
                              hipStream_t stream) {
  const float* x = (const float*)d_in[0];
  const int* ei = (const int*)d_in[1];
  const float* W1rel = (const float*)d_in[2];
  const float* b1 = (const float*)d_in[3];
  const float* W1root = (const float*)d_in[4];
  const float* W2rel = (const float*)d_in[5];
  const float* b2 = (const float*)d_in[6];
  const float* W2root = (const float*)d_in[7];
  const float* W3rel = (const float*)d_in[8];
  const float* b3 = (const float*)d_in[9];
  const float* W3root = (const float*)d_in[10];

  const int* src = ei;       // edge_index[0]
  const int* dst = ei + NE;  // edge_index[1]

  char* ws = (char*)d_ws;
  size_t off = 0;
  float* bufA = (float*)(ws + off); off += (size_t)NN * NF * 4;   // 51.2 MB
  float* bufB = (float*)(ws + off); off += (size_t)NN * NF * 4;   // 51.2 MB
  int* deg     = (int*)(ws + off);  off += (size_t)NN * 4;        // 400 KB
  int* offs    = (int*)(ws + off);  off += (size_t)NN * 4;        // 400 KB
  int* bcnt    = (int*)(ws + off);  off += 1024 * 4;
  int* boffs   = (int*)(ws + off);  off += 1024 * 4;
  int* bcursor = (int*)(ws + off);  off += 1024 * 4;
  float* S     = (float*)(ws + off); off += 256 * 4;
  int* packed  = (int*)(ws + off);  off += (size_t)NE * 4;        // 6.4 MB
  int* srcs    = packed;  // k_sort2 rewrites packed in place as sorted srcs
  float* outp = (float*)d_out;

  hipMemsetAsync(deg, 0, (size_t)NN * sizeof(int), stream);
  hipMemsetAsync(bcnt, 0, 1024 * sizeof(int), stream);
  hipMemsetAsync(S, 0, 256 * sizeof(float), stream);

  // build exact dst-sorted CSR: coarse bin (coalesced) then in-LDS exact sort
  k_hist2<<<391, 256, 0, stream>>>(src, dst, deg, bcnt);
  k_bscan<<<1, 256, 0, stream>>>(bcnt, boffs, bcursor);
  k_bin<<<(NE + CH - 1) / CH, 256, 0, stream>>>(src, dst, bcursor, packed);
  k_sort2<<<NBK, 256, 0, stream>>>(packed, boffs, offs);

  // layer 1: agg(x) -> bufA; h1 = relu(gemm) in-place into bufA
  k_agg<<<(NN + 3) / 4, 256, 0, stream>>>(x, offs, srcs, bufA);
  k_gemm<1><<<(NN + 63) / 64, 256, 0, stream>>>(bufA, x, W1rel, W1root, b1, bufA);

  // layer 2: agg(h1) -> bufB; h2 = relu(gemm) in-place into bufB
  k_agg<<<(NN + 3) / 4, 256, 0, stream>>>(bufA, offs, srcs, bufB);
  k_gemm<1><<<(NN + 63) / 64, 256, 0, stream>>>(bufB, bufA, W2rel, W2root, b2, bufB);

  // layer 3 collapsed
  k_reduce3<<<256, 256, 0, stream>>>(bufB, deg, S);
  k_final<<<1, 128, 0, stream>>>(S, W3rel, W3root, b3, outp);
}

// Round 5
// 405.273 us; speedup vs baseline: 7.3405x; 1.4698x over previous
//
#include <hip/hip_runtime.h>

#define NN 100000
#define NF 128
#define NE 1600000
#define NBK 782   // ceil(NN/128) buckets of 128 dst nodes
#define CH 8192   // edges per binning chunk
#define MAXB 2816 // max edges per bucket

typedef unsigned short ushort_t;
typedef __attribute__((ext_vector_type(8))) short bf16x8;
typedef __attribute__((ext_vector_type(4))) float f32x4;

__device__ inline ushort_t f2bf(float f) {  // RNE
  union { float f; unsigned u; } v; v.f = f;
  const unsigned r = v.u + 0x7FFFu + ((v.u >> 16) & 1u);
  return (ushort_t)(r >> 16);
}
__device__ inline float bf2f(ushort_t h) {
  union { unsigned u; float f; } v; v.u = ((unsigned)h) << 16;
  return v.f;
}

// --------------------------------------------------------------- hist + deg
__global__ __launch_bounds__(256) void k_hist2(const int* __restrict__ src,
                                               const int* __restrict__ dst,
                                               int* __restrict__ deg,
                                               int* __restrict__ bcnt) {
  __shared__ int h[1024];
  for (int i = threadIdx.x; i < 1024; i += 256) h[i] = 0;
  __syncthreads();
  const int gid = blockIdx.x * 256 + threadIdx.x;
  const int stride = gridDim.x * 256;
  for (int e = gid; e < NE; e += stride) {
    atomicAdd(&deg[src[e]], 1);
    atomicAdd(&h[dst[e] >> 7], 1);
  }
  __syncthreads();
  for (int i = threadIdx.x; i < NBK; i += 256)
    if (h[i]) atomicAdd(&bcnt[i], h[i]);
}

// ---------------------------------------------- block-wide exclusive scan
__device__ inline void block_scan(const int* hist, int* lofs, int* wsum) {
  const int t = threadIdx.x;
  const int b4 = t * 4;
  const int h0 = hist[b4], h1 = hist[b4 + 1], h2 = hist[b4 + 2], h3 = hist[b4 + 3];
  const int tsum = h0 + h1 + h2 + h3;
  const int lane = t & 63, w = t >> 6;
  int s = tsum;
#pragma unroll
  for (int o = 1; o < 64; o <<= 1) {
    const int u = __shfl_up(s, o);
    if (lane >= o) s += u;
  }
  if (lane == 63) wsum[w] = s;
  __syncthreads();
  int add = 0;
  for (int i = 0; i < w; ++i) add += wsum[i];
  const int ex = add + s - tsum;
  lofs[b4] = ex;
  lofs[b4 + 1] = ex + h0;
  lofs[b4 + 2] = ex + h0 + h1;
  lofs[b4 + 3] = ex + h0 + h1 + h2;
}

__global__ __launch_bounds__(256) void k_bscan(const int* __restrict__ bcnt,
                                               int* __restrict__ boffs,
                                               int* __restrict__ bcursor) {
  __shared__ int hist[1024];
  __shared__ int lofs[1024];
  __shared__ int wsum[4];
  const int t = threadIdx.x;
  for (int i = t; i < 1024; i += 256) hist[i] = (i < NBK) ? bcnt[i] : 0;
  __syncthreads();
  block_scan(hist, lofs, wsum);
  __syncthreads();
  for (int i = t; i < 1024; i += 256) {
    if (i <= NBK) boffs[i] = lofs[i];
    if (i < NBK) bcursor[i] = lofs[i];
  }
}

// ------------------------------------------------ LDS-staged bucket binning
__global__ __launch_bounds__(256) void k_bin(const int* __restrict__ src,
                                             const int* __restrict__ dst,
                                             int* __restrict__ bcursor,
                                             int* __restrict__ packed) {
  __shared__ int hist[1024];
  __shared__ int lofs[1024];
  __shared__ int wsum[4];
  __shared__ int gofs[NBK];
  __shared__ int list[CH];
  __shared__ unsigned short blist[CH];
  const int t = threadIdx.x;
  const int e0 = blockIdx.x * CH;
  const int n = min(CH, NE - e0);

  for (int i = t; i < 1024; i += 256) hist[i] = 0;
  __syncthreads();
  for (int i = t; i < n; i += 256) atomicAdd(&hist[dst[e0 + i] >> 7], 1);
  __syncthreads();
  block_scan(hist, lofs, wsum);
  __syncthreads();
  for (int b = t; b < NBK; b += 256) {
    const int cnt = hist[b];
    gofs[b] = cnt ? atomicAdd(&bcursor[b], cnt) : 0;
    hist[b] = 0;
  }
  __syncthreads();
  for (int i = t; i < n; i += 256) {
    const int d = dst[e0 + i];
    const int s = src[e0 + i];
    const int b = d >> 7;
    const int r = atomicAdd(&hist[b], 1);
    const int q = lofs[b] + r;
    list[q] = ((d & 127) << 17) | s;
    blist[q] = (unsigned short)b;
  }
  __syncthreads();
  for (int q = t; q < n; q += 256) {
    const int b = blist[q];
    packed[gofs[b] + (q - lofs[b])] = list[q];
  }
}

// --------------------------------- second-level sort: exact CSR per bucket
__global__ __launch_bounds__(256) void k_sort2(int* __restrict__ packed,
                                               const int* __restrict__ boffs,
                                               int* __restrict__ offs) {
  __shared__ int plist[MAXB];
  __shared__ int slist[MAXB];
  __shared__ int hist[128];
  __shared__ int lofs[128];
  __shared__ int wsum2[2];
  const int b = blockIdx.x, t = threadIdx.x;
  const int beg = boffs[b], end = boffs[b + 1];
  const int n = min(end - beg, MAXB);

  for (int i = t; i < n; i += 256) plist[i] = packed[beg + i];
  if (t < 128) hist[t] = 0;
  __syncthreads();
  for (int i = t; i < n; i += 256) atomicAdd(&hist[plist[i] >> 17], 1);
  __syncthreads();
  int s = (t < 128) ? hist[t] : 0;
  {
    const int lane = t & 63;
#pragma unroll
    for (int o = 1; o < 64; o <<= 1) {
      const int u = __shfl_up(s, o);
      if (lane >= o) s += u;
    }
    if (t < 128 && lane == 63) wsum2[t >> 6] = s;
  }
  __syncthreads();
  if (t < 128) {
    const int ex = s - hist[t] + ((t >= 64) ? wsum2[0] : 0);
    lofs[t] = ex;
    const int node = (b << 7) + t;
    if (node < NN) offs[node] = beg + ex;
    hist[t] = 0;
  }
  __syncthreads();
  for (int i = t; i < n; i += 256) {
    const int p = plist[i];
    const int ld = p >> 17;
    const int r = atomicAdd(&hist[ld], 1);
    slist[lofs[ld] + r] = p & 0x1FFFF;
  }
  __syncthreads();
  for (int i = t; i < n; i += 256) packed[beg + i] = slist[i];
}

// ---------------------------------------------------------- fp32 -> bf16
__global__ __launch_bounds__(256) void k_cvt(const float* __restrict__ in,
                                             ushort_t* __restrict__ out, int n4) {
  const int i = blockIdx.x * 256 + threadIdx.x;
  if (i < n4) {
    const float4 v = *reinterpret_cast<const float4*>(in + i * 4);
    ushort4 o;
    o.x = f2bf(v.x); o.y = f2bf(v.y); o.z = f2bf(v.z); o.w = f2bf(v.w);
    *reinterpret_cast<ushort4*>(out + i * 4) = o;
  }
}

// all four 128x128 weight mats in one launch; dst segments of 16384
__global__ __launch_bounds__(256) void k_cvtw(const float* __restrict__ w0,
                                              const float* __restrict__ w1,
                                              const float* __restrict__ w2,
                                              const float* __restrict__ w3,
                                              ushort_t* __restrict__ out) {
  const int i = blockIdx.x * 256 + threadIdx.x;  // 16384 threads
  out[i] = f2bf(w0[i]);
  out[16384 + i] = f2bf(w1[i]);
  out[32768 + i] = f2bf(w2[i]);
  out[49152 + i] = f2bf(w3[i]);
}

// --------------------------------------------- gather-based aggregation (bf16)
// one wave per dst node; lane handles 2 consecutive feats (256B/row coalesced)
__global__ __launch_bounds__(256) void k_agg(const ushort_t* __restrict__ feat,
                                             const int* __restrict__ offs,
                                             const int* __restrict__ srcs,
                                             ushort_t* __restrict__ out) {
  const int node = blockIdx.x * 4 + (threadIdx.x >> 6);
  if (node >= NN) return;
  const int lane = threadIdx.x & 63;
  const int c = lane * 2;
  const int beg = offs[node];
  const int end = (node == NN - 1) ? NE : offs[node + 1];

  float a0x = 0.f, a0y = 0.f, a1x = 0.f, a1y = 0.f;
  float a2x = 0.f, a2y = 0.f, a3x = 0.f, a3y = 0.f;
  int e = beg;
  for (; e + 4 <= end; e += 4) {
    const int s0 = srcs[e], s1 = srcs[e + 1], s2 = srcs[e + 2], s3 = srcs[e + 3];
    const ushort2 u0 = *reinterpret_cast<const ushort2*>(feat + s0 * NF + c);
    const ushort2 u1 = *reinterpret_cast<const ushort2*>(feat + s1 * NF + c);
    const ushort2 u2 = *reinterpret_cast<const ushort2*>(feat + s2 * NF + c);
    const ushort2 u3 = *reinterpret_cast<const ushort2*>(feat + s3 * NF + c);
    a0x += bf2f(u0.x); a0y += bf2f(u0.y);
    a1x += bf2f(u1.x); a1y += bf2f(u1.y);
    a2x += bf2f(u2.x); a2y += bf2f(u2.y);
    a3x += bf2f(u3.x); a3y += bf2f(u3.y);
  }
  for (; e < end; ++e) {
    const int s = srcs[e];
    const ushort2 u = *reinterpret_cast<const ushort2*>(feat + s * NF + c);
    a0x += bf2f(u.x); a0y += bf2f(u.y);
  }
  ushort2 r;
  r.x = f2bf((a0x + a1x) + (a2x + a3x));
  r.y = f2bf((a0y + a1y) + (a2y + a3y));
  *reinterpret_cast<ushort2*>(out + node * NF + c) = r;
}

// ------------------------------------------------------------- MFMA GEMM
// out[i][j] = act( A1[i,:]·B1[j,:] + A2[i,:]·B2[j,:] + bias[j] ), bf16 in,
// fp32 acc, bf16 out. Block: 64 nodes x 128 j, 4 waves (wave = 32 j).
// B frags (full K=256) preloaded to 64 VGPR; A staged in LDS (pitch 264).
template <int RELU>
__global__ __launch_bounds__(256) void k_gemm(const ushort_t* __restrict__ A1,
                                              const ushort_t* __restrict__ A2,
                                              const ushort_t* __restrict__ B1,
                                              const ushort_t* __restrict__ B2,
                                              const float* __restrict__ bias,
                                              ushort_t* __restrict__ out) {
  __shared__ ushort_t As[64][264];  // +8 pad: 2-way LDS conflict only
  const int tid = threadIdx.x;
  const int lane = tid & 63;
  const int wid = tid >> 6;
  const int bm = blockIdx.x * 64;

  // B fragments: j = wid*32 + nt*16 + (lane&15); k = ks*32 + (lane>>4)*8 + i
  const int jb = wid * 32 + (lane & 15);
  const int kc = (lane >> 4) * 8;
  bf16x8 bfrag[2][8];
#pragma unroll
  for (int nt = 0; nt < 2; ++nt) {
    const int j = jb + nt * 16;
#pragma unroll
    for (int ks = 0; ks < 4; ++ks) {
      bfrag[nt][ks] = *reinterpret_cast<const bf16x8*>(B1 + j * 128 + ks * 32 + kc);
      bfrag[nt][ks + 4] = *reinterpret_cast<const bf16x8*>(B2 + j * 128 + ks * 32 + kc);
    }
  }

  // stage A: 64 rows x (128|128) bf16
  {
    const int r = tid >> 2, p = tid & 3;
    const int node = bm + r;
#pragma unroll
    for (int s = 0; s < 2; ++s) {
      const ushort_t* __restrict__ sp = s ? A2 : A1;
#pragma unroll
      for (int q = 0; q < 4; ++q) {
        const int col = p * 32 + q * 8;
        bf16x8 v = (node < NN) ? *reinterpret_cast<const bf16x8*>(sp + node * 128 + col)
                               : (bf16x8)(short)0;
        *reinterpret_cast<bf16x8*>(&As[r][s * 128 + col]) = v;
      }
    }
  }
  __syncthreads();

  f32x4 acc[4][2];
#pragma unroll
  for (int mt = 0; mt < 4; ++mt) {
    acc[mt][0] = (f32x4)0.f;
    acc[mt][1] = (f32x4)0.f;
  }

  const int ar = lane & 15;
#pragma unroll
  for (int ks = 0; ks < 8; ++ks) {
#pragma unroll
    for (int mt = 0; mt < 4; ++mt) {
      const bf16x8 a = *reinterpret_cast<const bf16x8*>(&As[mt * 16 + ar][ks * 32 + kc]);
      acc[mt][0] = __builtin_amdgcn_mfma_f32_16x16x32_bf16(a, bfrag[0][ks], acc[mt][0], 0, 0, 0);
      acc[mt][1] = __builtin_amdgcn_mfma_f32_16x16x32_bf16(a, bfrag[1][ks], acc[mt][1], 0, 0, 0);
    }
  }

  // epilogue: C/D layout col=lane&15 (j), row=(lane>>4)*4+reg (node)
  const int rg = (lane >> 4) * 4;
#pragma unroll
  for (int nt = 0; nt < 2; ++nt) {
    const int j = jb + nt * 16;
    const float bv = bias[j];
#pragma unroll
    for (int mt = 0; mt < 4; ++mt) {
#pragma unroll
      for (int r = 0; r < 4; ++r) {
        const int node = bm + mt * 16 + rg + r;
        if (node < NN) {
          float v = acc[mt][nt][r] + bv;
          if (RELU) v = fmaxf(v, 0.f);
          out[node * 128 + j] = f2bf(v);
        }
      }
    }
  }
}

// ------------------------------------- layer-3 collapsed weighted reductions
__global__ __launch_bounds__(256) void k_reduce3(const ushort_t* __restrict__ h,
                                                 const int* __restrict__ deg,
                                                 float* __restrict__ S) {
  const int t = blockIdx.x * 256 + threadIdx.x;
  const int f = t & 127;
  const int i0 = t >> 7;
  float a1 = 0.f, a2 = 0.f;
  for (int i = i0; i < NN; i += 512) {
    const float v = bf2f(h[i * NF + f]);
    a1 += v;
    a2 += (float)deg[i] * v;
  }
  atomicAdd(&S[f], a1);
  atomicAdd(&S[128 + f], a2);
}

__global__ __launch_bounds__(128) void k_final(const float* __restrict__ S,
                                               const float* __restrict__ W3rel,
                                               const float* __restrict__ W3root,
                                               const float* __restrict__ b3,
                                               float* __restrict__ out) {
  const int f = threadIdx.x;
  float v = W3rel[f] * S[128 + f] + W3root[f] * S[f];
#pragma unroll
  for (int o = 32; o > 0; o >>= 1) v += __shfl_down(v, o);
  __shared__ float tmp[2];
  if ((f & 63) == 0) tmp[f >> 6] = v;
  __syncthreads();
  if (f == 0) out[0] = (tmp[0] + tmp[1]) * (1.0f / NN) + b3[0];
}

// ---------------------------------------------------------------------------
extern "C" void kernel_launch(void* const* d_in, const int* in_sizes, int n_in,
                              void* d_out, int out_size, void* d_ws, size_t ws_size,
                              hipStream_t stream) {
  const float* x = (const float*)d_in[0];
  const int* ei = (const int*)d_in[1];
  const float* W1rel = (const float*)d_in[2];
  const float* b1 = (const float*)d_in[3];
  const float* W1root = (const float*)d_in[4];
  const float* W2rel = (const float*)d_in[5];
  const float* b2 = (const float*)d_in[6];
  const float* W2root = (const float*)d_in[7];
  const float* W3rel = (const float*)d_in[8];
  const float* b3 = (const float*)d_in[9];
  const float* W3root = (const float*)d_in[10];

  const int* src = ei;       // edge_index[0]
  const int* dst = ei + NE;  // edge_index[1]

  char* ws = (char*)d_ws;
  size_t off = 0;
  ushort_t* xb   = (ushort_t*)(ws + off); off += (size_t)NN * NF * 2;  // 25.6 MB
  ushort_t* h1b  = (ushort_t*)(ws + off); off += (size_t)NN * NF * 2;  // 25.6 MB
  ushort_t* aggb = (ushort_t*)(ws + off); off += (size_t)NN * NF * 2;  // 25.6 MB
  ushort_t* Wb   = (ushort_t*)(ws + off); off += 65536 * 2;            // 128 KB
  int* deg     = (int*)(ws + off); off += (size_t)NN * 4;              // 400 KB
  int* offs    = (int*)(ws + off); off += (size_t)NN * 4;              // 400 KB
  int* bcnt    = (int*)(ws + off); off += 1024 * 4;
  int* boffs   = (int*)(ws + off); off += 1024 * 4;
  int* bcursor = (int*)(ws + off); off += 1024 * 4;
  float* S     = (float*)(ws + off); off += 256 * 4;
  int* packed  = (int*)(ws + off); off += (size_t)NE * 4;              // 6.4 MB
  int* srcs    = packed;            // k_sort2 rewrites packed in place
  ushort_t* h2b = xb;               // xb dead after gemm1 -> alias h2
  float* outp = (float*)d_out;

  hipMemsetAsync(deg, 0, (size_t)NN * sizeof(int), stream);
  hipMemsetAsync(bcnt, 0, 1024 * sizeof(int), stream);
  hipMemsetAsync(S, 0, 256 * sizeof(float), stream);

  // build exact dst-sorted CSR + conversions
  k_hist2<<<391, 256, 0, stream>>>(src, dst, deg, bcnt);
  k_bscan<<<1, 256, 0, stream>>>(bcnt, boffs, bcursor);
  k_bin<<<(NE + CH - 1) / CH, 256, 0, stream>>>(src, dst, bcursor, packed);
  k_sort2<<<NBK, 256, 0, stream>>>(packed, boffs, offs);
  k_cvt<<<(NN * NF / 4 + 255) / 256, 256, 0, stream>>>(x, xb, NN * NF / 4);
  k_cvtw<<<64, 256, 0, stream>>>(W1rel, W1root, W2rel, W2root, Wb);

  // layer 1
  k_agg<<<NN / 4, 256, 0, stream>>>(xb, offs, srcs, aggb);
  k_gemm<1><<<(NN + 63) / 64, 256, 0, stream>>>(aggb, xb, Wb, Wb + 16384, b1, h1b);

  // layer 2 (h2 aliases xb — xb no longer needed)
  k_agg<<<NN / 4, 256, 0, stream>>>(h1b, offs, srcs, aggb);
  k_gemm<1><<<(NN + 63) / 64, 256, 0, stream>>>(aggb, h1b, Wb + 32768, Wb + 49152, b2, h2b);

  // layer 3 collapsed
  k_reduce3<<<256, 256, 0, stream>>>(h2b, deg, S);
  k_final<<<1, 128, 0, stream>>>(S, W3rel, W3root, b3, outp);
}

// Round 6
// 298.253 us; speedup vs baseline: 9.9744x; 1.3588x over previous
//
#include <hip/hip_runtime.h>

#define NN 100000
#define NF 128
#define NE 1600000
#define NBK 782   // ceil(NN/128) buckets of 128 dst nodes
#define CH 4096   // edges per binning chunk
#define MAXB 2816 // padded region per bucket (mean 2046, ~17 sigma headroom)
#define RED_B 512 // blocks for dot3/esum partial reductions

typedef unsigned short ushort_t;
typedef __attribute__((ext_vector_type(8))) short bf16x8;
typedef __attribute__((ext_vector_type(4))) float f32x4;

__device__ inline ushort_t f2bf(float f) {  // RNE
  union { float f; unsigned u; } v; v.f = f;
  const unsigned r = v.u + 0x7FFFu + ((v.u >> 16) & 1u);
  return (ushort_t)(r >> 16);
}
__device__ inline float bf2f(ushort_t h) {
  union { unsigned u; float f; } v; v.u = ((unsigned)h) << 16;
  return v.f;
}

// ---------------------------------------------- block-wide exclusive scan
// 256 threads, 1024 padded elements, 4 contiguous per thread.
__device__ inline void block_scan(const int* hist, int* lofs, int* wsum) {
  const int t = threadIdx.x;
  const int b4 = t * 4;
  const int h0 = hist[b4], h1 = hist[b4 + 1], h2 = hist[b4 + 2], h3 = hist[b4 + 3];
  const int tsum = h0 + h1 + h2 + h3;
  const int lane = t & 63, w = t >> 6;
  int s = tsum;
#pragma unroll
  for (int o = 1; o < 64; o <<= 1) {
    const int u = __shfl_up(s, o);
    if (lane >= o) s += u;
  }
  if (lane == 63) wsum[w] = s;
  __syncthreads();
  int add = 0;
  for (int i = 0; i < w; ++i) add += wsum[i];
  const int ex = add + s - tsum;
  lofs[b4] = ex;
  lofs[b4 + 1] = ex + h0;
  lofs[b4 + 2] = ex + h0 + h1;
  lofs[b4 + 3] = ex + h0 + h1 + h2;
}

// ------------------------------------------------ LDS-staged bucket binning
// No pre-scan: bucket b owns padded region [b*MAXB, (b+1)*MAXB). Per chunk:
// LDS hist -> scan -> reserve via bcursor atomics -> local scatter ->
// coalesced-ish flush of packed ((dst&127)<<17 | src) words.
__global__ __launch_bounds__(256) void k_bin(const int* __restrict__ src,
                                             const int* __restrict__ dst,
                                             int* __restrict__ bcursor,
                                             int* __restrict__ packed) {
  __shared__ int hist[1024];
  __shared__ int lofs[1024];
  __shared__ int wsum[4];
  __shared__ int gofs[NBK];
  __shared__ int list[CH];
  __shared__ unsigned short blist[CH];
  const int t = threadIdx.x;
  const int e0 = blockIdx.x * CH;
  const int n = min(CH, NE - e0);

  for (int i = t; i < 1024; i += 256) hist[i] = 0;
  __syncthreads();
  for (int i = t; i < n; i += 256) atomicAdd(&hist[dst[e0 + i] >> 7], 1);
  __syncthreads();
  block_scan(hist, lofs, wsum);
  __syncthreads();
  for (int b = t; b < NBK; b += 256) {
    const int cnt = hist[b];
    gofs[b] = cnt ? atomicAdd(&bcursor[b], cnt) : 0;
    hist[b] = 0;
  }
  __syncthreads();
  for (int i = t; i < n; i += 256) {
    const int d = dst[e0 + i];
    const int s = src[e0 + i];
    const int b = d >> 7;
    const int r = atomicAdd(&hist[b], 1);
    const int q = lofs[b] + r;
    list[q] = ((d & 127) << 17) | s;
    blist[q] = (unsigned short)b;
  }
  __syncthreads();
  for (int q = t; q < n; q += 256) {
    const int b = blist[q];
    const int idx = gofs[b] + (q - lofs[b]);
    if (idx < MAXB) packed[b * MAXB + idx] = list[q];
  }
}

// --------------------------------- second-level sort: exact CSR per bucket
// One block per bucket. Exact-sorts its padded segment by 7-bit local dst,
// writes per-node [offs,ends) + coalesced srcs in place.
__global__ __launch_bounds__(256) void k_sort2(int* __restrict__ packed,
                                               const int* __restrict__ bcursor,
                                               int* __restrict__ offs,
                                               int* __restrict__ ends) {
  __shared__ int plist[MAXB];
  __shared__ int slist[MAXB];
  __shared__ int hist[128];
  __shared__ int lofs[128];
  __shared__ int wsum2[2];
  const int b = blockIdx.x, t = threadIdx.x;
  const int beg = b * MAXB;
  const int n = min(bcursor[b], MAXB);

  for (int i = t; i < n; i += 256) plist[i] = packed[beg + i];
  if (t < 128) hist[t] = 0;
  __syncthreads();
  for (int i = t; i < n; i += 256) atomicAdd(&hist[plist[i] >> 17], 1);
  __syncthreads();
  int s = (t < 128) ? hist[t] : 0;
  {
    const int lane = t & 63;
#pragma unroll
    for (int o = 1; o < 64; o <<= 1) {
      const int u = __shfl_up(s, o);
      if (lane >= o) s += u;
    }
    if (t < 128 && lane == 63) wsum2[t >> 6] = s;
  }
  __syncthreads();
  if (t < 128) {
    const int ex = s - hist[t] + ((t >= 64) ? wsum2[0] : 0);
    lofs[t] = ex;
    const int node = (b << 7) + t;
    if (node < NN) {
      offs[node] = beg + ex;
      ends[node] = beg + ex + hist[t];
    }
    hist[t] = 0;
  }
  __syncthreads();
  for (int i = t; i < n; i += 256) {
    const int p = plist[i];
    const int ld = p >> 17;
    const int r = atomicAdd(&hist[ld], 1);
    slist[lofs[ld] + r] = p & 0x1FFFF;
  }
  __syncthreads();
  for (int i = t; i < n; i += 256) packed[beg + i] = slist[i];
}

// ---------------------------------------------------------- fp32 -> bf16
__global__ __launch_bounds__(256) void k_cvt(const float* __restrict__ in,
                                             ushort_t* __restrict__ out, int n4) {
  const int i = blockIdx.x * 256 + threadIdx.x;
  if (i < n4) {
    const float4 v = *reinterpret_cast<const float4*>(in + i * 4);
    ushort4 o;
    o.x = f2bf(v.x); o.y = f2bf(v.y); o.z = f2bf(v.z); o.w = f2bf(v.w);
    *reinterpret_cast<ushort4*>(out + i * 4) = o;
  }
}

__global__ __launch_bounds__(256) void k_cvtw(const float* __restrict__ w0,
                                              const float* __restrict__ w1,
                                              const float* __restrict__ w2,
                                              const float* __restrict__ w3,
                                              ushort_t* __restrict__ out) {
  const int i = blockIdx.x * 256 + threadIdx.x;  // 16384 threads
  out[i] = f2bf(w0[i]);
  out[16384 + i] = f2bf(w1[i]);
  out[32768 + i] = f2bf(w2[i]);
  out[49152 + i] = f2bf(w3[i]);
}

// --------------------------------------------- gather-based aggregation (bf16)
__global__ __launch_bounds__(256) void k_agg(const ushort_t* __restrict__ feat,
                                             const int* __restrict__ offs,
                                             const int* __restrict__ ends,
                                             const int* __restrict__ srcs,
                                             ushort_t* __restrict__ out) {
  const int node = blockIdx.x * 4 + (threadIdx.x >> 6);
  if (node >= NN) return;
  const int lane = threadIdx.x & 63;
  const int c = lane * 2;
  const int beg = offs[node];
  const int end = ends[node];

  float a0x = 0.f, a0y = 0.f, a1x = 0.f, a1y = 0.f;
  float a2x = 0.f, a2y = 0.f, a3x = 0.f, a3y = 0.f;
  int e = beg;
  for (; e + 4 <= end; e += 4) {
    const int s0 = srcs[e], s1 = srcs[e + 1], s2 = srcs[e + 2], s3 = srcs[e + 3];
    const ushort2 u0 = *reinterpret_cast<const ushort2*>(feat + s0 * NF + c);
    const ushort2 u1 = *reinterpret_cast<const ushort2*>(feat + s1 * NF + c);
    const ushort2 u2 = *reinterpret_cast<const ushort2*>(feat + s2 * NF + c);
    const ushort2 u3 = *reinterpret_cast<const ushort2*>(feat + s3 * NF + c);
    a0x += bf2f(u0.x); a0y += bf2f(u0.y);
    a1x += bf2f(u1.x); a1y += bf2f(u1.y);
    a2x += bf2f(u2.x); a2y += bf2f(u2.y);
    a3x += bf2f(u3.x); a3y += bf2f(u3.y);
  }
  for (; e < end; ++e) {
    const int s = srcs[e];
    const ushort2 u = *reinterpret_cast<const ushort2*>(feat + s * NF + c);
    a0x += bf2f(u.x); a0y += bf2f(u.y);
  }
  ushort2 r;
  r.x = f2bf((a0x + a1x) + (a2x + a3x));
  r.y = f2bf((a0y + a1y) + (a2y + a3y));
  *reinterpret_cast<ushort2*>(out + node * NF + c) = r;
}

// ------------------------------------------------------------- MFMA GEMM
// out[i][j] = act( A1[i,:]·B1[j,:] + A2[i,:]·B2[j,:] + bias[j] ), bf16 in,
// fp32 acc, bf16 out. Block: 64 nodes x 128 j, 4 waves (wave = 32 j).
template <int RELU>
__global__ __launch_bounds__(256) void k_gemm(const ushort_t* __restrict__ A1,
                                              const ushort_t* __restrict__ A2,
                                              const ushort_t* __restrict__ B1,
                                              const ushort_t* __restrict__ B2,
                                              const float* __restrict__ bias,
                                              ushort_t* __restrict__ out) {
  __shared__ ushort_t As[64][264];  // +8 pad: 2-way LDS conflict only
  const int tid = threadIdx.x;
  const int lane = tid & 63;
  const int wid = tid >> 6;
  const int bm = blockIdx.x * 64;

  const int jb = wid * 32 + (lane & 15);
  const int kc = (lane >> 4) * 8;
  bf16x8 bfrag[2][8];
#pragma unroll
  for (int nt = 0; nt < 2; ++nt) {
    const int j = jb + nt * 16;
#pragma unroll
    for (int ks = 0; ks < 4; ++ks) {
      bfrag[nt][ks] = *reinterpret_cast<const bf16x8*>(B1 + j * 128 + ks * 32 + kc);
      bfrag[nt][ks + 4] = *reinterpret_cast<const bf16x8*>(B2 + j * 128 + ks * 32 + kc);
    }
  }

  {
    const int r = tid >> 2, p = tid & 3;
    const int node = bm + r;
#pragma unroll
    for (int s = 0; s < 2; ++s) {
      const ushort_t* __restrict__ sp = s ? A2 : A1;
#pragma unroll
      for (int q = 0; q < 4; ++q) {
        const int col = p * 32 + q * 8;
        bf16x8 v = (node < NN) ? *reinterpret_cast<const bf16x8*>(sp + node * 128 + col)
                               : (bf16x8)(short)0;
        *reinterpret_cast<bf16x8*>(&As[r][s * 128 + col]) = v;
      }
    }
  }
  __syncthreads();

  f32x4 acc[4][2];
#pragma unroll
  for (int mt = 0; mt < 4; ++mt) {
    acc[mt][0] = (f32x4)0.f;
    acc[mt][1] = (f32x4)0.f;
  }

  const int ar = lane & 15;
#pragma unroll
  for (int ks = 0; ks < 8; ++ks) {
#pragma unroll
    for (int mt = 0; mt < 4; ++mt) {
      const bf16x8 a = *reinterpret_cast<const bf16x8*>(&As[mt * 16 + ar][ks * 32 + kc]);
      acc[mt][0] = __builtin_amdgcn_mfma_f32_16x16x32_bf16(a, bfrag[0][ks], acc[mt][0], 0, 0, 0);
      acc[mt][1] = __builtin_amdgcn_mfma_f32_16x16x32_bf16(a, bfrag[1][ks], acc[mt][1], 0, 0, 0);
    }
  }

  const int rg = (lane >> 4) * 4;
#pragma unroll
  for (int nt = 0; nt < 2; ++nt) {
    const int j = jb + nt * 16;
    const float bv = bias[j];
#pragma unroll
    for (int mt = 0; mt < 4; ++mt) {
#pragma unroll
      for (int r = 0; r < 4; ++r) {
        const int node = bm + mt * 16 + rg + r;
        if (node < NN) {
          float v = acc[mt][nt][r] + bv;
          if (RELU) v = fmaxf(v, 0.f);
          out[node * 128 + j] = f2bf(v);
        }
      }
    }
  }
}

// ---------------------- layer-3: y1[i] = h2_i·W3rel ; P2 partials of Σ h2_i·W3root
__global__ __launch_bounds__(256) void k_dot3(const ushort_t* __restrict__ h,
                                              const float* __restrict__ W3rel,
                                              const float* __restrict__ W3root,
                                              float* __restrict__ y1,
                                              float* __restrict__ P2) {
  const int lane = threadIdx.x & 63;
  const int w = threadIdx.x >> 6;
  const int c = lane * 2;
  const float wr0 = W3rel[c], wr1 = W3rel[c + 1];
  const float wt0 = W3root[c], wt1 = W3root[c + 1];
  float p2 = 0.f;
  const int wstride = RED_B * 4;
  for (int node = blockIdx.x * 4 + w; node < NN; node += wstride) {
    const ushort2 u = *reinterpret_cast<const ushort2*>(h + node * NF + c);
    const float h0 = bf2f(u.x), h1 = bf2f(u.y);
    p2 += h0 * wt0 + h1 * wt1;          // no per-node reduce needed
    float v1 = h0 * wr0 + h1 * wr1;
#pragma unroll
    for (int o = 32; o > 0; o >>= 1) v1 += __shfl_down(v1, o);
    if (lane == 0) y1[node] = v1;
  }
  // block-reduce p2
#pragma unroll
  for (int o = 32; o > 0; o >>= 1) p2 += __shfl_down(p2, o);
  __shared__ float tmp[4];
  if (lane == 0) tmp[w] = p2;
  __syncthreads();
  if (threadIdx.x == 0)
    P2[blockIdx.x] = (tmp[0] + tmp[1]) + (tmp[2] + tmp[3]);
}

// --------------------------- T1 partials: Σ_e y1[src_e] (L2-resident table)
__global__ __launch_bounds__(256) void k_esum(const int* __restrict__ src,
                                              const float* __restrict__ y1,
                                              float* __restrict__ P1) {
  float p = 0.f;
  const int stride = RED_B * 256;
  for (int e = blockIdx.x * 256 + threadIdx.x; e < NE; e += stride)
    p += y1[src[e]];
#pragma unroll
  for (int o = 32; o > 0; o >>= 1) p += __shfl_down(p, o);
  __shared__ float tmp[4];
  const int lane = threadIdx.x & 63, w = threadIdx.x >> 6;
  if (lane == 0) tmp[w] = p;
  __syncthreads();
  if (threadIdx.x == 0)
    P1[blockIdx.x] = (tmp[0] + tmp[1]) + (tmp[2] + tmp[3]);
}

__global__ __launch_bounds__(256) void k_final(const float* __restrict__ P1,
                                               const float* __restrict__ P2,
                                               const float* __restrict__ b3,
                                               float* __restrict__ out) {
  const int t = threadIdx.x;
  float v = P1[t] + P1[t + 256] + P2[t] + P2[t + 256];
#pragma unroll
  for (int o = 32; o > 0; o >>= 1) v += __shfl_down(v, o);
  __shared__ float tmp[4];
  if ((t & 63) == 0) tmp[t >> 6] = v;
  __syncthreads();
  if (t == 0)
    out[0] = ((tmp[0] + tmp[1]) + (tmp[2] + tmp[3])) * (1.0f / NN) + b3[0];
}

// ---------------------------------------------------------------------------
extern "C" void kernel_launch(void* const* d_in, const int* in_sizes, int n_in,
                              void* d_out, int out_size, void* d_ws, size_t ws_size,
                              hipStream_t stream) {
  const float* x = (const float*)d_in[0];
  const int* ei = (const int*)d_in[1];
  const float* W1rel = (const float*)d_in[2];
  const float* b1 = (const float*)d_in[3];
  const float* W1root = (const float*)d_in[4];
  const float* W2rel = (const float*)d_in[5];
  const float* b2 = (const float*)d_in[6];
  const float* W2root = (const float*)d_in[7];
  const float* W3rel = (const float*)d_in[8];
  const float* b3 = (const float*)d_in[9];
  const float* W3root = (const float*)d_in[10];

  const int* src = ei;       // edge_index[0]
  const int* dst = ei + NE;  // edge_index[1]

  char* ws = (char*)d_ws;
  size_t off = 0;
  ushort_t* xb   = (ushort_t*)(ws + off); off += (size_t)NN * NF * 2;  // 25.6 MB
  ushort_t* h1b  = (ushort_t*)(ws + off); off += (size_t)NN * NF * 2;  // 25.6 MB
  ushort_t* aggb = (ushort_t*)(ws + off); off += (size_t)NN * NF * 2;  // 25.6 MB
  ushort_t* Wb   = (ushort_t*)(ws + off); off += 65536 * 2;            // 128 KB
  int* offs    = (int*)(ws + off); off += (size_t)NN * 4;              // 400 KB
  int* ends    = (int*)(ws + off); off += (size_t)NN * 4;              // 400 KB
  float* y1    = (float*)(ws + off); off += (size_t)NN * 4;            // 400 KB
  int* bcursor = (int*)(ws + off); off += 1024 * 4;
  float* P1    = (float*)(ws + off); off += RED_B * 4;
  float* P2    = (float*)(ws + off); off += RED_B * 4;
  int* packed  = (int*)(ws + off); off += (size_t)NBK * MAXB * 4;      // 8.8 MB
  int* srcs    = packed;            // k_sort2 rewrites packed in place
  ushort_t* h2b = xb;               // xb dead after gemm1 -> alias h2
  float* outp = (float*)d_out;

  hipMemsetAsync(bcursor, 0, 1024 * sizeof(int), stream);

  // CSR build (padded regions, no pre-scan) + conversions
  k_bin<<<(NE + CH - 1) / CH, 256, 0, stream>>>(src, dst, bcursor, packed);
  k_sort2<<<NBK, 256, 0, stream>>>(packed, bcursor, offs, ends);
  k_cvt<<<(NN * NF / 4 + 255) / 256, 256, 0, stream>>>(x, xb, NN * NF / 4);
  k_cvtw<<<64, 256, 0, stream>>>(W1rel, W1root, W2rel, W2root, Wb);

  // layer 1
  k_agg<<<NN / 4, 256, 0, stream>>>(xb, offs, ends, srcs, aggb);
  k_gemm<1><<<(NN + 63) / 64, 256, 0, stream>>>(aggb, xb, Wb, Wb + 16384, b1, h1b);

  // layer 2 (h2 aliases xb)
  k_agg<<<NN / 4, 256, 0, stream>>>(h1b, offs, ends, srcs, aggb);
  k_gemm<1><<<(NN + 63) / 64, 256, 0, stream>>>(aggb, h1b, Wb + 32768, Wb + 49152, b2, h2b);

  // layer 3 collapsed: scalar projections + L2-resident scalar gather
  k_dot3<<<RED_B, 256, 0, stream>>>(h2b, W3rel, W3root, y1, P2);
  k_esum<<<RED_B, 256, 0, stream>>>(src, y1, P1);
  k_final<<<1, 256, 0, stream>>>(P1, P2, b3, outp);
}